// Round 22
// baseline (626.846 us; speedup 1.0000x reference)
//
#include <hip/hip_runtime.h>
#include <hip/hip_bf16.h>
#include <stdint.h>

typedef __hip_bfloat16 bf16;
typedef short bf16x8 __attribute__((ext_vector_type(8)));
typedef float f32x4 __attribute__((ext_vector_type(4)));

#define MFMA16(a, b, c) __builtin_amdgcn_mfma_f32_16x16x32_bf16((a), (b), (c), 0, 0, 0)

__device__ __forceinline__ void gload16(const void* g, void* l) {
  __builtin_amdgcn_global_load_lds((const __attribute__((address_space(1))) void*)g,
                                   (__attribute__((address_space(3))) void*)l,
                                   16, 0, 0);
}

__device__ __forceinline__ void stv(float* p, float v) { *p = v; }
__device__ __forceinline__ void stv(bf16* p, float v) { *p = __float2bfloat16(v); }

// 16-lane (DPP-row) reductions: quad_perm xor1, xor2, then row_ror 4, 8.
__device__ __forceinline__ float row_max16(float v) {
  int t = __builtin_amdgcn_update_dpp(0, __float_as_int(v), 0xB1, 0xF, 0xF, true);
  v = fmaxf(v, __int_as_float(t));
  t = __builtin_amdgcn_update_dpp(0, __float_as_int(v), 0x4E, 0xF, 0xF, true);
  v = fmaxf(v, __int_as_float(t));
  t = __builtin_amdgcn_update_dpp(0, __float_as_int(v), 0x124, 0xF, 0xF, true);
  v = fmaxf(v, __int_as_float(t));
  t = __builtin_amdgcn_update_dpp(0, __float_as_int(v), 0x128, 0xF, 0xF, true);
  v = fmaxf(v, __int_as_float(t));
  return v;
}
__device__ __forceinline__ float row_sum16(float v) {
  int t = __builtin_amdgcn_update_dpp(0, __float_as_int(v), 0xB1, 0xF, 0xF, true);
  v += __int_as_float(t);
  t = __builtin_amdgcn_update_dpp(0, __float_as_int(v), 0x4E, 0xF, 0xF, true);
  v += __int_as_float(t);
  t = __builtin_amdgcn_update_dpp(0, __float_as_int(v), 0x124, 0xF, 0xF, true);
  v += __int_as_float(t);
  t = __builtin_amdgcn_update_dpp(0, __float_as_int(v), 0x128, 0xF, 0xF, true);
  v += __int_as_float(t);
  return v;
}

// ---------------------------------------------------------------------------
// Merged fp32 -> bf16 casts for x, wqkv, wo (one launch, block-range split).
// ---------------------------------------------------------------------------
__global__ void cast3_f32_bf16(const float* __restrict__ in0, bf16* __restrict__ out0,
                               long n0, const float* __restrict__ in1,
                               bf16* __restrict__ out1, long n1,
                               const float* __restrict__ in2, bf16* __restrict__ out2,
                               long n2) {
  const float* in;
  bf16* out;
  long n, base;
  int nb;
  if (blockIdx.x < 1024) {
    in = in0; out = out0; n = n0; base = blockIdx.x; nb = 1024;
  } else if (blockIdx.x < 2560) {
    in = in1; out = out1; n = n1; base = blockIdx.x - 1024; nb = 1536;
  } else {
    in = in2; out = out2; n = n2; base = blockIdx.x - 2560; nb = 1024;
  }
  const long stride = (long)nb * blockDim.x * 8;
  for (long i = (base * blockDim.x + threadIdx.x) * 8L; i < n; i += stride) {
    const float4 a = *(const float4*)&in[i];
    const float4 b = *(const float4*)&in[i + 4];
    bf16 t[8];
    t[0] = __float2bfloat16(a.x); t[1] = __float2bfloat16(a.y);
    t[2] = __float2bfloat16(a.z); t[3] = __float2bfloat16(a.w);
    t[4] = __float2bfloat16(b.x); t[5] = __float2bfloat16(b.y);
    t[6] = __float2bfloat16(b.z); t[7] = __float2bfloat16(b.w);
    *(bf16x8*)&out[i] = *(const bf16x8*)t;
  }
}

// ---------------------------------------------------------------------------
// GEMM round-22: r18 4-phase/K-tile (BK=64, 2dbuf) with BALANCED ds_reads
// (8/8/8/0): each fragment read in the latest phase before first use.
// P1: a0+b0; P2: a2+a1; P3: b1+a3; P4: none.
// Stages: B(t+1)@P1,P2 (other buffer); A(t+2)@P4 only (A(t)'s last read a3
// is in P3 -> P3's lgkm(0)+end-barrier proves chip-wide retirement before
// the P4 overwrite). Top vmcnt(4) drains B(t+1), keeps A(t+2) in flight.
// ---------------------------------------------------------------------------
template <typename OutT>
__global__ __launch_bounds__(512, 2) void gemm256(const bf16* __restrict__ A,
                                                  const bf16* __restrict__ B,
                                                  OutT* __restrict__ C,
                                                  int M, int N, int K) {
  const int nbn = N >> 8;
  const int nwg = gridDim.x;
  const int wg = blockIdx.x;
  const int cpx = nwg >> 3;                    // nwg % 8 == 0 guaranteed
  const int swz = (wg & 7) * cpx + (wg >> 3);  // XCD-aware swizzle (bijective)
  const int bm = swz / nbn;
  const int bn = swz - bm * nbn;

  __shared__ bf16 As[2][256][64];  // 64 KB (2 halves of 128 rows each)
  __shared__ bf16 Bs[2][256][64];  // 64 KB

  const int tid = threadIdx.x;
  const int wave = tid >> 6, lane = tid & 63;
  const int lo = lane & 15, hi = lane >> 4;
  const int wm = wave >> 2, wn = wave & 3;

  const bf16* Ag = A + (long)(bm * 256) * K;
  const bf16* Bg = B + (long)(bn * 256) * K;

  int srow[2], scol[2], sdst[2];
#pragma unroll
  for (int j = 0; j < 2; j++) {
    const int c = j * 512 + tid;
    const int row = c >> 3;                  // 0..127 within half
    srow[j] = row;
    scol[j] = ((c & 7) ^ (row & 7)) * 8;     // inverse-swizzled global col
    sdst[j] = (j * 512 + wave * 64) * 8;     // wave-uniform LDS base (elems)
  }

#define STG(G, S, kt, h)                                                      \
  {                                                                           \
    _Pragma("unroll") for (int j = 0; j < 2; j++)                             \
        gload16((G) + (long)((h)*128 + srow[j]) * K + (kt) + scol[j],         \
                (S) + (h)*8192 + sdst[j]);                                    \
  }

  f32x4 acc[8][4] = {};
  const int NT = K >> 6;

  // prologue: tile0 full (8 loads), tile1 A halves (4 loads)
  STG(Ag, &As[0][0][0], 0, 0); STG(Ag, &As[0][0][0], 0, 1);
  STG(Bg, &Bs[0][0][0], 0, 0); STG(Bg, &Bs[0][0][0], 0, 1);
  STG(Ag, &As[1][0][0], 64, 0); STG(Ag, &As[1][0][0], 64, 1);

#pragma unroll 1
  for (int t = 0; t < NT; ++t) {
    if (t >= NT - 1) asm volatile("s_waitcnt vmcnt(0)" ::: "memory");
    else             asm volatile("s_waitcnt vmcnt(4)" ::: "memory");
    __builtin_amdgcn_s_barrier();

    const bf16* Ab = &As[t & 1][0][0];
    const bf16* Bb = &Bs[t & 1][0][0];
    bf16* SAn = &As[t & 1][0][0];        // A(t+2) dest (A(t) dead after P3)
    bf16* SBn = &Bs[(t + 1) & 1][0][0];  // B(t+1) dest (other buffer)
    const int kt1 = (t + 1) * 64, kt2 = (t + 2) * 64;
    const bool s1 = (t + 1 < NT), s2 = (t + 2 < NT);
    const int c0 = (hi ^ (lo & 7)) * 8;        // ks0 swizzled col
    const int c1 = ((4 + hi) ^ (lo & 7)) * 8;  // ks1 swizzled col

    bf16x8 a0[4], a1[4], a2[4], a3[4], b0[4], b1[4];

    // ---- P1: read a0 (4) + b0 (4); stage B-lo(t+1); 16 MFMA (a0 x b0) ----
#pragma unroll
    for (int m = 0; m < 4; m++)
      a0[m] = *(const bf16x8*)&Ab[(wm * 128 + m * 16 + lo) * 64 + c0];
#pragma unroll
    for (int n = 0; n < 4; n++)
      b0[n] = *(const bf16x8*)&Bb[(wn * 64 + n * 16 + lo) * 64 + c0];
    if (s1) STG(Bg, SBn, kt1, 0);
    __builtin_amdgcn_s_barrier();
    asm volatile("s_waitcnt lgkmcnt(0)" ::: "memory");
    __builtin_amdgcn_sched_barrier(0);
    __builtin_amdgcn_s_setprio(1);
#pragma unroll
    for (int m = 0; m < 4; m++)
#pragma unroll
      for (int n = 0; n < 4; n++) acc[m][n] = MFMA16(a0[m], b0[n], acc[m][n]);
    __builtin_amdgcn_s_setprio(0);
    __builtin_amdgcn_s_barrier();

    // ---- P2: read a2 (4) + a1 (4); stage B-hi(t+1); 16 MFMA (a2 x b0) ----
#pragma unroll
    for (int m = 0; m < 4; m++) {
      a2[m] = *(const bf16x8*)&Ab[(wm * 128 + 64 + m * 16 + lo) * 64 + c0];
      a1[m] = *(const bf16x8*)&Ab[(wm * 128 + m * 16 + lo) * 64 + c1];
    }
    if (s1) STG(Bg, SBn, kt1, 1);
    __builtin_amdgcn_s_barrier();
    asm volatile("s_waitcnt lgkmcnt(0)" ::: "memory");
    __builtin_amdgcn_sched_barrier(0);
    __builtin_amdgcn_s_setprio(1);
#pragma unroll
    for (int m = 0; m < 4; m++)
#pragma unroll
      for (int n = 0; n < 4; n++) acc[4 + m][n] = MFMA16(a2[m], b0[n], acc[4 + m][n]);
    __builtin_amdgcn_s_setprio(0);
    __builtin_amdgcn_s_barrier();

    // ---- P3: read b1 (4) + a3 (4); 16 MFMA (a1 x b1). A(t),B(t) dead ----
#pragma unroll
    for (int n = 0; n < 4; n++)
      b1[n] = *(const bf16x8*)&Bb[(wn * 64 + n * 16 + lo) * 64 + c1];
#pragma unroll
    for (int m = 0; m < 4; m++)
      a3[m] = *(const bf16x8*)&Ab[(wm * 128 + 64 + m * 16 + lo) * 64 + c1];
    __builtin_amdgcn_s_barrier();
    asm volatile("s_waitcnt lgkmcnt(0)" ::: "memory");
    __builtin_amdgcn_sched_barrier(0);
    __builtin_amdgcn_s_setprio(1);
#pragma unroll
    for (int m = 0; m < 4; m++)
#pragma unroll
      for (int n = 0; n < 4; n++) acc[m][n] = MFMA16(a1[m], b1[n], acc[m][n]);
    __builtin_amdgcn_s_setprio(0);
    __builtin_amdgcn_s_barrier();

    // ---- P4: stage A(t+2) both halves (all A(t) reads retired chip-wide
    //          via P3's lgkm(0) + end barrier); 16 MFMA (a3 x b1) ----
    if (s2) { STG(Ag, SAn, kt2, 0); STG(Ag, SAn, kt2, 1); }
    __builtin_amdgcn_s_barrier();
    __builtin_amdgcn_s_setprio(1);
#pragma unroll
    for (int m = 0; m < 4; m++)
#pragma unroll
      for (int n = 0; n < 4; n++) acc[4 + m][n] = MFMA16(a3[m], b1[n], acc[4 + m][n]);
    __builtin_amdgcn_s_setprio(0);
    // tile-top vmcnt+barrier closes the tile
  }
#undef STG

  const long crow0 = (long)bm * 256 + wm * 128;
  const long ccol0 = (long)bn * 256 + wn * 64;
#pragma unroll
  for (int m = 0; m < 8; m++)
#pragma unroll
    for (int n = 0; n < 4; n++)
#pragma unroll
      for (int r = 0; r < 4; r++)
        stv(&C[(crow0 + m * 16 + hi * 4 + r) * (long)N + ccol0 + n * 16 + lo],
            acc[m][n][r]);
}

// ---------------------------------------------------------------------------
// Fused RoPE (in-place, Q scaled) + V transpose (disjoint qkv columns).
// Blocks [0,4096) = rope rows; [4096,5120) = vtrans 64x64 tiles. block 256.
// ---------------------------------------------------------------------------
__global__ void rope_vtrans(bf16* __restrict__ qkv, bf16* __restrict__ Vt) {
  __shared__ bf16 tile[64][65];
  if (blockIdx.x < 4096) {
    const int row = blockIdx.x;
    const int t = row & 2047;
    const float scale = 0.08838834764831845f;  // 128^-0.5
    for (int p = threadIdx.x; p < 40 * 64; p += blockDim.x) {
      const int sh = p >> 6, j = p & 63;
      const int kvh = sh / 5, slot = sh - kvh * 5;
      const long base = (long)row * 6144 + kvh * 768 + slot * 128 + j;
      const float x1 = __bfloat162float(qkv[base]);
      const float x2 = __bfloat162float(qkv[base + 64]);
      const float inv = __expf(-(float)j * 0.14391156831212787f);  // ln(1e4)/64
      const float ang = (float)t * inv;
      const float c = cosf(ang), s = sinf(ang);
      float o1 = x1 * c - x2 * s;
      float o2 = x2 * c + x1 * s;
      if (slot < 4) { o1 *= scale; o2 *= scale; }
      qkv[base] = __float2bfloat16(o1);
      qkv[base + 64] = __float2bfloat16(o2);
    }
  } else {
    const int id = blockIdx.x - 4096;
    const int tt = id & 31, dd = (id >> 5) & 1, bk = id >> 6;
    const int kvh = bk & 7, b = bk >> 3;
    const int tx = threadIdx.x & 63, ty = threadIdx.x >> 6;
    const bf16* src =
        qkv + ((long)(b * 2048 + tt * 64)) * 6144 + kvh * 768 + 640 + dd * 64;
    for (int r = ty; r < 64; r += 4) tile[r][tx] = src[(long)r * 6144 + tx];
    __syncthreads();
    bf16* dst = Vt + ((long)bk * 128 + dd * 64) * 2048 + tt * 64;
    for (int r = ty; r < 64; r += 4) dst[(long)r * 2048 + tx] = tile[tx][r];
  }
}

// ---------------------------------------------------------------------------
// Causal GQA flash attention (r18-verified): LDS-staged K/V, KVBLK=64,
// defer-max + DPP reductions. grid 512, block 256. XCD remap -> K/V in L2.
// ---------------------------------------------------------------------------
__global__ __launch_bounds__(256) void attn(const bf16* __restrict__ qkv,
                                            const bf16* __restrict__ Vt,
                                            bf16* __restrict__ Ctx) {
  const int lin = blockIdx.x;                 // 0..511
  const int c = (lin & 7) * 64 + (lin >> 3);  // XCD-contiguous chunks of 64
  const int z = c & 31;
  const int kvh = (c >> 5) & 7;
  const int b = c >> 8;

  const int tid = threadIdx.x;
  const int wave = tid >> 6;
  const int lane = tid & 63;
  const int h = kvh * 4 + wave;
  const int lo = lane & 15, hi = lane >> 4;

  const bf16* Qb = qkv + (long)b * 2048 * 6144 + kvh * 768 + wave * 128;
  const bf16* Kb = qkv + (long)b * 2048 * 6144 + kvh * 768 + 512;
  const bf16* Vb = Vt + ((long)(b * 8 + kvh)) * 128 * 2048;

  __shared__ bf16 Kl[2][64][128];   // 32 KB
  __shared__ bf16 Vl[2][128][64];   // 32 KB
  __shared__ bf16 Plds[4][32][40];  // 10 KB, per-wave

  const int kr0 = tid >> 4;
  const int kc = ((tid & 15) ^ (kr0 & 15)) * 8;
  const int vr0 = tid >> 3;
  const int vc = ((tid & 7) ^ (vr0 & 7)) * 8;
  const int wbase = wave * 512;

#define STAGE_KV(bufi, k0_)                                                    \
  {                                                                            \
    _Pragma("unroll") for (int cl = 0; cl < 4; cl++)                           \
        gload16(Kb + (long)((k0_) + cl * 16 + kr0) * 6144 + kc,                \
                &Kl[bufi][0][0] + cl * 2048 + wbase);                          \
    _Pragma("unroll") for (int cl = 0; cl < 4; cl++)                           \
        gload16(Vb + (long)(cl * 32 + vr0) * 2048 + (k0_) + vc,                \
                &Vl[bufi][0][0] + cl * 2048 + wbase);                          \
  }

#pragma unroll 1
  for (int pass = 0; pass < 2; ++pass) {
    const int qw = pass ? 63 - z : z;
    const int q0 = qw * 32;
    const int nkt = (qw >> 1) + 1;  // 64-wide tiles

    bf16x8 qf[2][4];
#pragma unroll
    for (int qb = 0; qb < 2; qb++)
#pragma unroll
      for (int dc = 0; dc < 4; dc++)
        qf[qb][dc] =
            *(const bf16x8*)&Qb[(long)(q0 + qb * 16 + lo) * 6144 + dc * 32 + hi * 8];

    f32x4 acc[2][8] = {};
    float mrow[2][4], lrow[2][4];
#pragma unroll
    for (int qb = 0; qb < 2; qb++)
#pragma unroll
      for (int r = 0; r < 4; r++) {
        mrow[qb][r] = -1e30f;
        lrow[qb][r] = 0.0f;
      }

    STAGE_KV(0, 0);
    if (nkt > 1) STAGE_KV(1, 64);

#pragma unroll 1
    for (int kt = 0; kt < nkt; ++kt) {
      if (kt < nkt - 1) asm volatile("s_waitcnt vmcnt(8)" ::: "memory");
      else              asm volatile("s_waitcnt vmcnt(0)" ::: "memory");
      __builtin_amdgcn_s_barrier();

      const int bi = kt & 1;
      const int k0 = kt * 64;

      f32x4 sacc[2][4] = {};
      __builtin_amdgcn_s_setprio(1);
#pragma unroll
      for (int kb = 0; kb < 4; kb++)
#pragma unroll
        for (int dc = 0; dc < 4; dc++) {
          const int row = kb * 16 + lo;
          const int p = (dc * 4 + hi) ^ lo;  // row&15 == lo
          const bf16x8 kf = *(const bf16x8*)&Kl[bi][row][p * 8];
          sacc[0][kb] = MFMA16(qf[0][dc], kf, sacc[0][kb]);
          sacc[1][kb] = MFMA16(qf[1][dc], kf, sacc[1][kb]);
        }
      __builtin_amdgcn_s_setprio(0);

      if (kt == nkt - 1) {  // diagonal region: mask k > q
#pragma unroll
        for (int qb = 0; qb < 2; qb++)
#pragma unroll
          for (int kb = 0; kb < 4; kb++) {
            const int q = q0 + qb * 16 + hi * 4;
            const int k = k0 + kb * 16 + lo;
#pragma unroll
            for (int r = 0; r < 4; r++)
              if (k > q + r) sacc[qb][kb][r] = -1e30f;
          }
      }

      // defer-max: lane-local excess check (no cross-lane ops)
      float ex = -1.0f;
#pragma unroll
      for (int qb = 0; qb < 2; qb++)
#pragma unroll
        for (int kb = 0; kb < 4; kb++)
#pragma unroll
          for (int r = 0; r < 4; r++)
            ex = fmaxf(ex, sacc[qb][kb][r] - mrow[qb][r]);

      if (!__all(ex <= 0.0f)) {
        float sf[2][4];
#pragma unroll
        for (int qb = 0; qb < 2; qb++)
#pragma unroll
          for (int r = 0; r < 4; r++) {
            const float pm = row_max16(
                fmaxf(fmaxf(sacc[qb][0][r], sacc[qb][1][r]),
                      fmaxf(sacc[qb][2][r], sacc[qb][3][r])));
            const float mn = fmaxf(mrow[qb][r], pm);
            sf[qb][r] = __expf(mrow[qb][r] - mn);
            mrow[qb][r] = mn;
            lrow[qb][r] *= sf[qb][r];
          }
#pragma unroll
        for (int qb = 0; qb < 2; qb++)
#pragma unroll
          for (int dt = 0; dt < 8; dt++)
#pragma unroll
            for (int r = 0; r < 4; r++) acc[qb][dt][r] *= sf[qb][r];
      }

      // exp in place + one row-sum per (qb,r) per 64 keys
#pragma unroll
      for (int qb = 0; qb < 2; qb++)
#pragma unroll
        for (int r = 0; r < 4; r++) {
          float s0 = __expf(sacc[qb][0][r] - mrow[qb][r]);
          float s1 = __expf(sacc[qb][1][r] - mrow[qb][r]);
          float s2 = __expf(sacc[qb][2][r] - mrow[qb][r]);
          float s3 = __expf(sacc[qb][3][r] - mrow[qb][r]);
          sacc[qb][0][r] = s0; sacc[qb][1][r] = s1;
          sacc[qb][2][r] = s2; sacc[qb][3][r] = s3;
          lrow[qb][r] += row_sum16((s0 + s1) + (s2 + s3));
        }

      // PV in two 32-wide chunks through per-wave Plds (in-order: safe)
#pragma unroll
      for (int ks = 0; ks < 2; ks++) {
#pragma unroll
        for (int qb = 0; qb < 2; qb++)
#pragma unroll
          for (int r = 0; r < 4; r++) {
            Plds[wave][qb * 16 + hi * 4 + r][lo] =
                __float2bfloat16(sacc[qb][ks * 2][r]);
            Plds[wave][qb * 16 + hi * 4 + r][16 + lo] =
                __float2bfloat16(sacc[qb][ks * 2 + 1][r]);
          }

        bf16x8 pa[2];
#pragma unroll
        for (int qb = 0; qb < 2; qb++)
          pa[qb] = *(const bf16x8*)&Plds[wave][qb * 16 + lo][hi * 8];

        __builtin_amdgcn_s_setprio(1);
#pragma unroll
        for (int dt = 0; dt < 8; dt++) {
          const int row = dt * 16 + lo;
          const int p = (ks * 4 + hi) ^ (row & 7);
          const bf16x8 vf = *(const bf16x8*)&Vl[bi][row][p * 8];
          acc[0][dt] = MFMA16(pa[0], vf, acc[0][dt]);
          acc[1][dt] = MFMA16(pa[1], vf, acc[1][dt]);
        }
        __builtin_amdgcn_s_setprio(0);
      }

      asm volatile("s_waitcnt lgkmcnt(0)" ::: "memory");
      __builtin_amdgcn_s_barrier();
      if (kt + 2 < nkt) STAGE_KV(bi, (kt + 2) * 64);
    }

    // epilogue: reciprocal once per row, then 64 muls
#pragma unroll
    for (int qb = 0; qb < 2; qb++)
#pragma unroll
      for (int r = 0; r < 4; r++) {
        const float rl = 1.0f / lrow[qb][r];
#pragma unroll
        for (int dt = 0; dt < 8; dt++) {
          const float o = acc[qb][dt][r] * rl;
          const long row = (long)b * 2048 + q0 + qb * 16 + hi * 4 + r;
          Ctx[row * 4096 + h * 128 + dt * 16 + lo] = __float2bfloat16(o);
        }
      }
  }
#undef STAGE_KV
}

// ---------------------------------------------------------------------------

extern "C" void kernel_launch(void* const* d_in, const int* in_sizes, int n_in,
                              void* d_out, int out_size, void* d_ws, size_t ws_size,
                              hipStream_t stream) {
  (void)in_sizes; (void)n_in; (void)out_size; (void)ws_size;
  const float* x = (const float*)d_in[0];      // [2,2048,4096] fp32
  const float* wqkv = (const float*)d_in[1];   // [6144,4096] fp32
  const float* wo = (const float*)d_in[2];     // [4096,4096] fp32
  float* out = (float*)d_out;                  // [2,2048,4096] fp32

  const long NX = 4096L * 4096;
  const long NW1 = 6144L * 4096;

  const size_t XB_B = (size_t)NX * 2;          // 33.6 MB
  const size_t WQ_B = (size_t)NW1 * 2;         // 50.3 MB
  const size_t QKV_B = WQ_B;                   // 50.3 MB
  const size_t VT_B = 16ULL * 128 * 2048 * 2;  // 8.4 MB

  char* w = (char*)d_ws;
  bf16* xb = (bf16*)w;
  bf16* wqkvb = (bf16*)(w + XB_B);             // later: ctx
  bf16* qkvp = (bf16*)(w + XB_B + WQ_B);
  bf16* Vtp = (bf16*)(w + XB_B + WQ_B + QKV_B);
  bf16* wob = (bf16*)(w + XB_B + WQ_B + QKV_B + VT_B);  // own slot (176MB peak)
  bf16* ctx = wqkvb;

  // 1. merged casts for x, wqkv, wo (one launch)
  cast3_f32_bf16<<<3584, 256, 0, stream>>>(x, xb, NX, wqkv, wqkvb, NW1, wo, wob, NX);

  // 2. QKV projection: qkv[4096,6144] = xb @ wqkvb^T   (16x24 = 384 tiles)
  gemm256<bf16><<<16 * 24, 512, 0, stream>>>(xb, wqkvb, qkvp, 4096, 6144, 4096);

  // 3. fused RoPE (Q scaled, in-place) + V transpose (disjoint columns)
  rope_vtrans<<<4096 + 1024, 256, 0, stream>>>(qkvp, Vtp);

  // 4. attention -> ctx (wqkvb's space, dead after GEMM1)
  attn<<<dim3(512), 256, 0, stream>>>(qkvp, Vtp, ctx);

  // 5. output projection: out(fp32) = ctx @ wob^T  (256 blocks = 1 round)
  gemm256<float><<<16 * 16, 512, 0, stream>>>(ctx, wob, out, 4096, 4096, 4096);
}

// Round 23
// 603.377 us; speedup vs baseline: 1.0389x; 1.0389x over previous
//
#include <hip/hip_runtime.h>
#include <hip/hip_bf16.h>
#include <stdint.h>

typedef __hip_bfloat16 bf16;
typedef short bf16x8 __attribute__((ext_vector_type(8)));
typedef float f32x4 __attribute__((ext_vector_type(4)));

#define MFMA16(a, b, c) __builtin_amdgcn_mfma_f32_16x16x32_bf16((a), (b), (c), 0, 0, 0)

__device__ __forceinline__ void gload16(const void* g, void* l) {
  __builtin_amdgcn_global_load_lds((const __attribute__((address_space(1))) void*)g,
                                   (__attribute__((address_space(3))) void*)l,
                                   16, 0, 0);
}

__device__ __forceinline__ void stv(float* p, float v) { *p = v; }
__device__ __forceinline__ void stv(bf16* p, float v) { *p = __float2bfloat16(v); }

// 16-lane (DPP-row) reductions: quad_perm xor1, xor2, then row_ror 4, 8.
__device__ __forceinline__ float row_max16(float v) {
  int t = __builtin_amdgcn_update_dpp(0, __float_as_int(v), 0xB1, 0xF, 0xF, true);
  v = fmaxf(v, __int_as_float(t));
  t = __builtin_amdgcn_update_dpp(0, __float_as_int(v), 0x4E, 0xF, 0xF, true);
  v = fmaxf(v, __int_as_float(t));
  t = __builtin_amdgcn_update_dpp(0, __float_as_int(v), 0x124, 0xF, 0xF, true);
  v = fmaxf(v, __int_as_float(t));
  t = __builtin_amdgcn_update_dpp(0, __float_as_int(v), 0x128, 0xF, 0xF, true);
  v = fmaxf(v, __int_as_float(t));
  return v;
}
__device__ __forceinline__ float row_sum16(float v) {
  int t = __builtin_amdgcn_update_dpp(0, __float_as_int(v), 0xB1, 0xF, 0xF, true);
  v += __int_as_float(t);
  t = __builtin_amdgcn_update_dpp(0, __float_as_int(v), 0x4E, 0xF, 0xF, true);
  v += __int_as_float(t);
  t = __builtin_amdgcn_update_dpp(0, __float_as_int(v), 0x124, 0xF, 0xF, true);
  v += __int_as_float(t);
  t = __builtin_amdgcn_update_dpp(0, __float_as_int(v), 0x128, 0xF, 0xF, true);
  v += __int_as_float(t);
  return v;
}

// ---------------------------------------------------------------------------
// Merged fp32 -> bf16 casts for x, wqkv, wo (one launch, block-range split).
// ---------------------------------------------------------------------------
__global__ void cast3_f32_bf16(const float* __restrict__ in0, bf16* __restrict__ out0,
                               long n0, const float* __restrict__ in1,
                               bf16* __restrict__ out1, long n1,
                               const float* __restrict__ in2, bf16* __restrict__ out2,
                               long n2) {
  const float* in;
  bf16* out;
  long n, base;
  int nb;
  if (blockIdx.x < 1024) {
    in = in0; out = out0; n = n0; base = blockIdx.x; nb = 1024;
  } else if (blockIdx.x < 2560) {
    in = in1; out = out1; n = n1; base = blockIdx.x - 1024; nb = 1536;
  } else {
    in = in2; out = out2; n = n2; base = blockIdx.x - 2560; nb = 1024;
  }
  const long stride = (long)nb * blockDim.x * 8;
  for (long i = (base * blockDim.x + threadIdx.x) * 8L; i < n; i += stride) {
    const float4 a = *(const float4*)&in[i];
    const float4 b = *(const float4*)&in[i + 4];
    bf16 t[8];
    t[0] = __float2bfloat16(a.x); t[1] = __float2bfloat16(a.y);
    t[2] = __float2bfloat16(a.z); t[3] = __float2bfloat16(a.w);
    t[4] = __float2bfloat16(b.x); t[5] = __float2bfloat16(b.y);
    t[6] = __float2bfloat16(b.z); t[7] = __float2bfloat16(b.w);
    *(bf16x8*)&out[i] = *(const bf16x8*)t;
  }
}

// ---------------------------------------------------------------------------
// GEMM (r18-verified schedule): 4-phase/K-tile, BK=64, 2dbuf, 256x256 tile.
// P1: a0,a1 (8 reads) + b0 (4), stage B-lo(t+1); P2: a2,a3 (8), stage
// B-hi(t+1); P3: b1 (4), stage A-lo(t+2); P4: stage A-hi(t+2).
// Top-of-tile vmcnt(4); per-phase lgkm(0)+barriers (r14 race proofs).
// ---------------------------------------------------------------------------
template <typename OutT>
__global__ __launch_bounds__(512, 2) void gemm256(const bf16* __restrict__ A,
                                                  const bf16* __restrict__ B,
                                                  OutT* __restrict__ C,
                                                  int M, int N, int K) {
  const int nbn = N >> 8;
  const int nwg = gridDim.x;
  const int wg = blockIdx.x;
  const int cpx = nwg >> 3;                    // nwg % 8 == 0 guaranteed
  const int swz = (wg & 7) * cpx + (wg >> 3);  // XCD-aware swizzle (bijective)
  const int bm = swz / nbn;
  const int bn = swz - bm * nbn;

  __shared__ bf16 As[2][256][64];  // 64 KB (2 halves of 128 rows each)
  __shared__ bf16 Bs[2][256][64];  // 64 KB

  const int tid = threadIdx.x;
  const int wave = tid >> 6, lane = tid & 63;
  const int lo = lane & 15, hi = lane >> 4;
  const int wm = wave >> 2, wn = wave & 3;

  const bf16* Ag = A + (long)(bm * 256) * K;
  const bf16* Bg = B + (long)(bn * 256) * K;

  int srow[2], scol[2], sdst[2];
#pragma unroll
  for (int j = 0; j < 2; j++) {
    const int c = j * 512 + tid;
    const int row = c >> 3;                  // 0..127 within half
    srow[j] = row;
    scol[j] = ((c & 7) ^ (row & 7)) * 8;     // inverse-swizzled global col
    sdst[j] = (j * 512 + wave * 64) * 8;     // wave-uniform LDS base (elems)
  }

#define STG(G, S, kt, h)                                                      \
  {                                                                           \
    _Pragma("unroll") for (int j = 0; j < 2; j++)                             \
        gload16((G) + (long)((h)*128 + srow[j]) * K + (kt) + scol[j],         \
                (S) + (h)*8192 + sdst[j]);                                    \
  }

  f32x4 acc[8][4] = {};
  const int NT = K >> 6;

  // prologue: tile0 full (8 loads), tile1 A halves (4 loads)
  STG(Ag, &As[0][0][0], 0, 0); STG(Ag, &As[0][0][0], 0, 1);
  STG(Bg, &Bs[0][0][0], 0, 0); STG(Bg, &Bs[0][0][0], 0, 1);
  STG(Ag, &As[1][0][0], 64, 0); STG(Ag, &As[1][0][0], 64, 1);

#pragma unroll 1
  for (int t = 0; t < NT; ++t) {
    if (t >= NT - 1) asm volatile("s_waitcnt vmcnt(0)" ::: "memory");
    else             asm volatile("s_waitcnt vmcnt(4)" ::: "memory");
    __builtin_amdgcn_s_barrier();

    const bf16* Ab = &As[t & 1][0][0];
    const bf16* Bb = &Bs[t & 1][0][0];
    bf16* SAn = &As[t & 1][0][0];        // A(t+2) dest (dead after P2)
    bf16* SBn = &Bs[(t + 1) & 1][0][0];  // B(t+1) dest (other buffer)
    const int kt1 = (t + 1) * 64, kt2 = (t + 2) * 64;
    const bool s1 = (t + 1 < NT), s2 = (t + 2 < NT);
    const int c0 = (hi ^ (lo & 7)) * 8;        // ks0 swizzled col
    const int c1 = ((4 + hi) ^ (lo & 7)) * 8;  // ks1 swizzled col

    bf16x8 a0[4], a1[4], a2[4], a3[4], b0[4], b1[4];

    // ---- P1: af m0-3 both ks (8) + bfr ks0 (4); stage B-lo(t+1) ----
#pragma unroll
    for (int m = 0; m < 4; m++) {
      const int row = (wm * 128 + m * 16 + lo) * 64;
      a0[m] = *(const bf16x8*)&Ab[row + c0];
      a1[m] = *(const bf16x8*)&Ab[row + c1];
    }
#pragma unroll
    for (int n = 0; n < 4; n++)
      b0[n] = *(const bf16x8*)&Bb[(wn * 64 + n * 16 + lo) * 64 + c0];
    if (s1) STG(Bg, SBn, kt1, 0);
    __builtin_amdgcn_s_barrier();
    asm volatile("s_waitcnt lgkmcnt(0)" ::: "memory");
    __builtin_amdgcn_sched_barrier(0);
    __builtin_amdgcn_s_setprio(1);
#pragma unroll
    for (int m = 0; m < 4; m++)
#pragma unroll
      for (int n = 0; n < 4; n++) acc[m][n] = MFMA16(a0[m], b0[n], acc[m][n]);
    __builtin_amdgcn_s_setprio(0);
    __builtin_amdgcn_s_barrier();

    // ---- P2: af m4-7 both ks (8); stage B-hi(t+1) ----
#pragma unroll
    for (int m = 0; m < 4; m++) {
      const int row = (wm * 128 + 64 + m * 16 + lo) * 64;
      a2[m] = *(const bf16x8*)&Ab[row + c0];
      a3[m] = *(const bf16x8*)&Ab[row + c1];
    }
    if (s1) STG(Bg, SBn, kt1, 1);
    __builtin_amdgcn_s_barrier();
    asm volatile("s_waitcnt lgkmcnt(0)" ::: "memory");
    __builtin_amdgcn_sched_barrier(0);
    __builtin_amdgcn_s_setprio(1);
#pragma unroll
    for (int m = 0; m < 4; m++)
#pragma unroll
      for (int n = 0; n < 4; n++) acc[4 + m][n] = MFMA16(a2[m], b0[n], acc[4 + m][n]);
    __builtin_amdgcn_s_setprio(0);
    __builtin_amdgcn_s_barrier();

    // ---- P3: bfr ks1 (4); stage A-lo(t+2) (A(t) dead after P2) ----
#pragma unroll
    for (int n = 0; n < 4; n++)
      b1[n] = *(const bf16x8*)&Bb[(wn * 64 + n * 16 + lo) * 64 + c1];
    if (s2) STG(Ag, SAn, kt2, 0);
    __builtin_amdgcn_s_barrier();
    asm volatile("s_waitcnt lgkmcnt(0)" ::: "memory");
    __builtin_amdgcn_sched_barrier(0);
    __builtin_amdgcn_s_setprio(1);
#pragma unroll
    for (int m = 0; m < 4; m++)
#pragma unroll
      for (int n = 0; n < 4; n++) acc[m][n] = MFMA16(a1[m], b1[n], acc[m][n]);
    __builtin_amdgcn_s_setprio(0);
    __builtin_amdgcn_s_barrier();

    // ---- P4: no reads; stage A-hi(t+2) ----
    if (s2) STG(Ag, SAn, kt2, 1);
    __builtin_amdgcn_s_barrier();
    __builtin_amdgcn_s_setprio(1);
#pragma unroll
    for (int m = 0; m < 4; m++)
#pragma unroll
      for (int n = 0; n < 4; n++) acc[4 + m][n] = MFMA16(a3[m], b1[n], acc[4 + m][n]);
    __builtin_amdgcn_s_setprio(0);
    // tile-top vmcnt+barrier closes the tile
  }
#undef STG

  const long crow0 = (long)bm * 256 + wm * 128;
  const long ccol0 = (long)bn * 256 + wn * 64;
#pragma unroll
  for (int m = 0; m < 8; m++)
#pragma unroll
    for (int n = 0; n < 4; n++)
#pragma unroll
      for (int r = 0; r < 4; r++)
        stv(&C[(crow0 + m * 16 + hi * 4 + r) * (long)N + ccol0 + n * 16 + lo],
            acc[m][n][r]);
}

// ---------------------------------------------------------------------------
// Fused RoPE (in-place, Q scaled) + V transpose (disjoint qkv columns).
// Blocks [0,4096) = rope rows; [4096,5120) = vtrans 64x64 tiles. block 256.
// ---------------------------------------------------------------------------
__global__ void rope_vtrans(bf16* __restrict__ qkv, bf16* __restrict__ Vt) {
  __shared__ bf16 tile[64][65];
  if (blockIdx.x < 4096) {
    const int row = blockIdx.x;
    const int t = row & 2047;
    const float scale = 0.08838834764831845f;  // 128^-0.5
    for (int p = threadIdx.x; p < 40 * 64; p += blockDim.x) {
      const int sh = p >> 6, j = p & 63;
      const int kvh = sh / 5, slot = sh - kvh * 5;
      const long base = (long)row * 6144 + kvh * 768 + slot * 128 + j;
      const float x1 = __bfloat162float(qkv[base]);
      const float x2 = __bfloat162float(qkv[base + 64]);
      const float inv = __expf(-(float)j * 0.14391156831212787f);  // ln(1e4)/64
      const float ang = (float)t * inv;
      const float c = cosf(ang), s = sinf(ang);
      float o1 = x1 * c - x2 * s;
      float o2 = x2 * c + x1 * s;
      if (slot < 4) { o1 *= scale; o2 *= scale; }
      qkv[base] = __float2bfloat16(o1);
      qkv[base + 64] = __float2bfloat16(o2);
    }
  } else {
    const int id = blockIdx.x - 4096;
    const int tt = id & 31, dd = (id >> 5) & 1, bk = id >> 6;
    const int kvh = bk & 7, b = bk >> 3;
    const int tx = threadIdx.x & 63, ty = threadIdx.x >> 6;
    const bf16* src =
        qkv + ((long)(b * 2048 + tt * 64)) * 6144 + kvh * 768 + 640 + dd * 64;
    for (int r = ty; r < 64; r += 4) tile[r][tx] = src[(long)r * 6144 + tx];
    __syncthreads();
    bf16* dst = Vt + ((long)bk * 128 + dd * 64) * 2048 + tt * 64;
    for (int r = ty; r < 64; r += 4) dst[(long)r * 2048 + tx] = tile[tx][r];
  }
}

// ---------------------------------------------------------------------------
// Causal GQA flash attention (r18-verified): LDS-staged K/V, KVBLK=64,
// defer-max + DPP reductions. grid 512, block 256. XCD remap -> K/V in L2.
// ---------------------------------------------------------------------------
__global__ __launch_bounds__(256) void attn(const bf16* __restrict__ qkv,
                                            const bf16* __restrict__ Vt,
                                            bf16* __restrict__ Ctx) {
  const int lin = blockIdx.x;                 // 0..511
  const int c = (lin & 7) * 64 + (lin >> 3);  // XCD-contiguous chunks of 64
  const int z = c & 31;
  const int kvh = (c >> 5) & 7;
  const int b = c >> 8;

  const int tid = threadIdx.x;
  const int wave = tid >> 6;
  const int lane = tid & 63;
  const int h = kvh * 4 + wave;
  const int lo = lane & 15, hi = lane >> 4;

  const bf16* Qb = qkv + (long)b * 2048 * 6144 + kvh * 768 + wave * 128;
  const bf16* Kb = qkv + (long)b * 2048 * 6144 + kvh * 768 + 512;
  const bf16* Vb = Vt + ((long)(b * 8 + kvh)) * 128 * 2048;

  __shared__ bf16 Kl[2][64][128];   // 32 KB
  __shared__ bf16 Vl[2][128][64];   // 32 KB
  __shared__ bf16 Plds[4][32][40];  // 10 KB, per-wave

  const int kr0 = tid >> 4;
  const int kc = ((tid & 15) ^ (kr0 & 15)) * 8;
  const int vr0 = tid >> 3;
  const int vc = ((tid & 7) ^ (vr0 & 7)) * 8;
  const int wbase = wave * 512;

#define STAGE_KV(bufi, k0_)                                                    \
  {                                                                            \
    _Pragma("unroll") for (int cl = 0; cl < 4; cl++)                           \
        gload16(Kb + (long)((k0_) + cl * 16 + kr0) * 6144 + kc,                \
                &Kl[bufi][0][0] + cl * 2048 + wbase);                          \
    _Pragma("unroll") for (int cl = 0; cl < 4; cl++)                           \
        gload16(Vb + (long)(cl * 32 + vr0) * 2048 + (k0_) + vc,                \
                &Vl[bufi][0][0] + cl * 2048 + wbase);                          \
  }

#pragma unroll 1
  for (int pass = 0; pass < 2; ++pass) {
    const int qw = pass ? 63 - z : z;
    const int q0 = qw * 32;
    const int nkt = (qw >> 1) + 1;  // 64-wide tiles

    bf16x8 qf[2][4];
#pragma unroll
    for (int qb = 0; qb < 2; qb++)
#pragma unroll
      for (int dc = 0; dc < 4; dc++)
        qf[qb][dc] =
            *(const bf16x8*)&Qb[(long)(q0 + qb * 16 + lo) * 6144 + dc * 32 + hi * 8];

    f32x4 acc[2][8] = {};
    float mrow[2][4], lrow[2][4];
#pragma unroll
    for (int qb = 0; qb < 2; qb++)
#pragma unroll
      for (int r = 0; r < 4; r++) {
        mrow[qb][r] = -1e30f;
        lrow[qb][r] = 0.0f;
      }

    STAGE_KV(0, 0);
    if (nkt > 1) STAGE_KV(1, 64);

#pragma unroll 1
    for (int kt = 0; kt < nkt; ++kt) {
      if (kt < nkt - 1) asm volatile("s_waitcnt vmcnt(8)" ::: "memory");
      else              asm volatile("s_waitcnt vmcnt(0)" ::: "memory");
      __builtin_amdgcn_s_barrier();

      const int bi = kt & 1;
      const int k0 = kt * 64;

      f32x4 sacc[2][4] = {};
      __builtin_amdgcn_s_setprio(1);
#pragma unroll
      for (int kb = 0; kb < 4; kb++)
#pragma unroll
        for (int dc = 0; dc < 4; dc++) {
          const int row = kb * 16 + lo;
          const int p = (dc * 4 + hi) ^ lo;  // row&15 == lo
          const bf16x8 kf = *(const bf16x8*)&Kl[bi][row][p * 8];
          sacc[0][kb] = MFMA16(qf[0][dc], kf, sacc[0][kb]);
          sacc[1][kb] = MFMA16(qf[1][dc], kf, sacc[1][kb]);
        }
      __builtin_amdgcn_s_setprio(0);

      if (kt == nkt - 1) {  // diagonal region: mask k > q
#pragma unroll
        for (int qb = 0; qb < 2; qb++)
#pragma unroll
          for (int kb = 0; kb < 4; kb++) {
            const int q = q0 + qb * 16 + hi * 4;
            const int k = k0 + kb * 16 + lo;
#pragma unroll
            for (int r = 0; r < 4; r++)
              if (k > q + r) sacc[qb][kb][r] = -1e30f;
          }
      }

      // defer-max: lane-local excess check (no cross-lane ops)
      float ex = -1.0f;
#pragma unroll
      for (int qb = 0; qb < 2; qb++)
#pragma unroll
        for (int kb = 0; kb < 4; kb++)
#pragma unroll
          for (int r = 0; r < 4; r++)
            ex = fmaxf(ex, sacc[qb][kb][r] - mrow[qb][r]);

      if (!__all(ex <= 0.0f)) {
        float sf[2][4];
#pragma unroll
        for (int qb = 0; qb < 2; qb++)
#pragma unroll
          for (int r = 0; r < 4; r++) {
            const float pm = row_max16(
                fmaxf(fmaxf(sacc[qb][0][r], sacc[qb][1][r]),
                      fmaxf(sacc[qb][2][r], sacc[qb][3][r])));
            const float mn = fmaxf(mrow[qb][r], pm);
            sf[qb][r] = __expf(mrow[qb][r] - mn);
            mrow[qb][r] = mn;
            lrow[qb][r] *= sf[qb][r];
          }
#pragma unroll
        for (int qb = 0; qb < 2; qb++)
#pragma unroll
          for (int dt = 0; dt < 8; dt++)
#pragma unroll
            for (int r = 0; r < 4; r++) acc[qb][dt][r] *= sf[qb][r];
      }

      // exp in place + one row-sum per (qb,r) per 64 keys
#pragma unroll
      for (int qb = 0; qb < 2; qb++)
#pragma unroll
        for (int r = 0; r < 4; r++) {
          float s0 = __expf(sacc[qb][0][r] - mrow[qb][r]);
          float s1 = __expf(sacc[qb][1][r] - mrow[qb][r]);
          float s2 = __expf(sacc[qb][2][r] - mrow[qb][r]);
          float s3 = __expf(sacc[qb][3][r] - mrow[qb][r]);
          sacc[qb][0][r] = s0; sacc[qb][1][r] = s1;
          sacc[qb][2][r] = s2; sacc[qb][3][r] = s3;
          lrow[qb][r] += row_sum16((s0 + s1) + (s2 + s3));
        }

      // PV in two 32-wide chunks through per-wave Plds (in-order: safe)
#pragma unroll
      for (int ks = 0; ks < 2; ks++) {
#pragma unroll
        for (int qb = 0; qb < 2; qb++)
#pragma unroll
          for (int r = 0; r < 4; r++) {
            Plds[wave][qb * 16 + hi * 4 + r][lo] =
                __float2bfloat16(sacc[qb][ks * 2][r]);
            Plds[wave][qb * 16 + hi * 4 + r][16 + lo] =
                __float2bfloat16(sacc[qb][ks * 2 + 1][r]);
          }

        bf16x8 pa[2];
#pragma unroll
        for (int qb = 0; qb < 2; qb++)
          pa[qb] = *(const bf16x8*)&Plds[wave][qb * 16 + lo][hi * 8];

        __builtin_amdgcn_s_setprio(1);
#pragma unroll
        for (int dt = 0; dt < 8; dt++) {
          const int row = dt * 16 + lo;
          const int p = (ks * 4 + hi) ^ (row & 7);
          const bf16x8 vf = *(const bf16x8*)&Vl[bi][row][p * 8];
          acc[0][dt] = MFMA16(pa[0], vf, acc[0][dt]);
          acc[1][dt] = MFMA16(pa[1], vf, acc[1][dt]);
        }
        __builtin_amdgcn_s_setprio(0);
      }

      asm volatile("s_waitcnt lgkmcnt(0)" ::: "memory");
      __builtin_amdgcn_s_barrier();
      if (kt + 2 < nkt) STAGE_KV(bi, (kt + 2) * 64);
    }

    // epilogue: reciprocal once per row, then 64 muls
#pragma unroll
    for (int qb = 0; qb < 2; qb++)
#pragma unroll
      for (int r = 0; r < 4; r++) {
        const float rl = 1.0f / lrow[qb][r];
#pragma unroll
        for (int dt = 0; dt < 8; dt++) {
          const float o = acc[qb][dt][r] * rl;
          const long row = (long)b * 2048 + q0 + qb * 16 + hi * 4 + r;
          Ctx[row * 4096 + h * 128 + dt * 16 + lo] = __float2bfloat16(o);
        }
      }
  }
#undef STAGE_KV
}

// ---------------------------------------------------------------------------

extern "C" void kernel_launch(void* const* d_in, const int* in_sizes, int n_in,
                              void* d_out, int out_size, void* d_ws, size_t ws_size,
                              hipStream_t stream) {
  (void)in_sizes; (void)n_in; (void)out_size; (void)ws_size;
  const float* x = (const float*)d_in[0];      // [2,2048,4096] fp32
  const float* wqkv = (const float*)d_in[1];   // [6144,4096] fp32
  const float* wo = (const float*)d_in[2];     // [4096,4096] fp32
  float* out = (float*)d_out;                  // [2,2048,4096] fp32

  const long NX = 4096L * 4096;
  const long NW1 = 6144L * 4096;

  const size_t XB_B = (size_t)NX * 2;          // 33.6 MB
  const size_t WQ_B = (size_t)NW1 * 2;         // 50.3 MB
  const size_t QKV_B = WQ_B;                   // 50.3 MB
  const size_t VT_B = 16ULL * 128 * 2048 * 2;  // 8.4 MB

  char* w = (char*)d_ws;
  bf16* xb = (bf16*)w;
  bf16* wqkvb = (bf16*)(w + XB_B);             // later: ctx
  bf16* qkvp = (bf16*)(w + XB_B + WQ_B);
  bf16* Vtp = (bf16*)(w + XB_B + WQ_B + QKV_B);
  bf16* wob = (bf16*)(w + XB_B + WQ_B + QKV_B + VT_B);  // own slot (176MB peak)
  bf16* ctx = wqkvb;

  // 1. merged casts for x, wqkv, wo (one launch)
  cast3_f32_bf16<<<3584, 256, 0, stream>>>(x, xb, NX, wqkv, wqkvb, NW1, wo, wob, NX);

  // 2. QKV projection: qkv[4096,6144] = xb @ wqkvb^T   (16x24 = 384 tiles)
  gemm256<bf16><<<16 * 24, 512, 0, stream>>>(xb, wqkvb, qkvp, 4096, 6144, 4096);

  // 3. fused RoPE (Q scaled, in-place) + V transpose (disjoint columns)
  rope_vtrans<<<4096 + 1024, 256, 0, stream>>>(qkvp, Vtp);

  // 4. attention -> ctx (wqkvb's space, dead after GEMM1)
  attn<<<dim3(512), 256, 0, stream>>>(qkvp, Vtp, ctx);

  // 5. output projection: out(fp32) = ctx @ wob^T  (256 blocks = 1 round)
  gemm256<float><<<16 * 16, 512, 0, stream>>>(ctx, wob, out, 4096, 4096, 4096);
}

// Round 24
// 582.753 us; speedup vs baseline: 1.0757x; 1.0354x over previous
//
#include <hip/hip_runtime.h>
#include <hip/hip_bf16.h>
#include <stdint.h>

typedef __hip_bfloat16 bf16;
typedef short bf16x8 __attribute__((ext_vector_type(8)));
typedef float f32x4 __attribute__((ext_vector_type(4)));

#define MFMA16(a, b, c) __builtin_amdgcn_mfma_f32_16x16x32_bf16((a), (b), (c), 0, 0, 0)

__device__ __forceinline__ void gload16(const void* g, void* l) {
  __builtin_amdgcn_global_load_lds((const __attribute__((address_space(1))) void*)g,
                                   (__attribute__((address_space(3))) void*)l,
                                   16, 0, 0);
}

__device__ __forceinline__ void stv(float* p, float v) { *p = v; }
__device__ __forceinline__ void stv(bf16* p, float v) { *p = __float2bfloat16(v); }

// 16-lane (DPP-row) reductions: quad_perm xor1, xor2, then row_ror 4, 8.
__device__ __forceinline__ float row_max16(float v) {
  int t = __builtin_amdgcn_update_dpp(0, __float_as_int(v), 0xB1, 0xF, 0xF, true);
  v = fmaxf(v, __int_as_float(t));
  t = __builtin_amdgcn_update_dpp(0, __float_as_int(v), 0x4E, 0xF, 0xF, true);
  v = fmaxf(v, __int_as_float(t));
  t = __builtin_amdgcn_update_dpp(0, __float_as_int(v), 0x124, 0xF, 0xF, true);
  v = fmaxf(v, __int_as_float(t));
  t = __builtin_amdgcn_update_dpp(0, __float_as_int(v), 0x128, 0xF, 0xF, true);
  v = fmaxf(v, __int_as_float(t));
  return v;
}
__device__ __forceinline__ float row_sum16(float v) {
  int t = __builtin_amdgcn_update_dpp(0, __float_as_int(v), 0xB1, 0xF, 0xF, true);
  v += __int_as_float(t);
  t = __builtin_amdgcn_update_dpp(0, __float_as_int(v), 0x4E, 0xF, 0xF, true);
  v += __int_as_float(t);
  t = __builtin_amdgcn_update_dpp(0, __float_as_int(v), 0x124, 0xF, 0xF, true);
  v += __int_as_float(t);
  t = __builtin_amdgcn_update_dpp(0, __float_as_int(v), 0x128, 0xF, 0xF, true);
  v += __int_as_float(t);
  return v;
}

// ---------------------------------------------------------------------------
// Merged fp32 -> bf16 casts for x and wqkv (one launch, block-range split).
// ---------------------------------------------------------------------------
__global__ void cast2_f32_bf16(const float* __restrict__ in0, bf16* __restrict__ out0,
                               long n0, const float* __restrict__ in1,
                               bf16* __restrict__ out1, long n1) {
  const float* in;
  bf16* out;
  long n, base;
  int nb;
  if (blockIdx.x < 1024) { in = in0; out = out0; n = n0; base = blockIdx.x; nb = 1024; }
  else                   { in = in1; out = out1; n = n1; base = blockIdx.x - 1024; nb = 2048; }
  const long stride = (long)nb * blockDim.x * 8;
  for (long i = (base * blockDim.x + threadIdx.x) * 8L; i < n; i += stride) {
    const float4 a = *(const float4*)&in[i];
    const float4 b = *(const float4*)&in[i + 4];
    bf16 t[8];
    t[0] = __float2bfloat16(a.x); t[1] = __float2bfloat16(a.y);
    t[2] = __float2bfloat16(a.z); t[3] = __float2bfloat16(a.w);
    t[4] = __float2bfloat16(b.x); t[5] = __float2bfloat16(b.y);
    t[6] = __float2bfloat16(b.z); t[7] = __float2bfloat16(b.w);
    *(bf16x8*)&out[i] = *(const bf16x8*)t;
  }
}

// single-array cast (wo) -- deliberately launched AFTER GEMM1 so its traffic
// does not evict xb/wqkvb from L2/L3 (r23 lesson).
__global__ void cast_f32_bf16(const float* __restrict__ in, bf16* __restrict__ out,
                              long n) {
  const long stride = (long)gridDim.x * blockDim.x * 8;
  for (long i = ((long)blockIdx.x * blockDim.x + threadIdx.x) * 8; i < n; i += stride) {
    const float4 a = *(const float4*)&in[i];
    const float4 b = *(const float4*)&in[i + 4];
    bf16 t[8];
    t[0] = __float2bfloat16(a.x); t[1] = __float2bfloat16(a.y);
    t[2] = __float2bfloat16(a.z); t[3] = __float2bfloat16(a.w);
    t[4] = __float2bfloat16(b.x); t[5] = __float2bfloat16(b.y);
    t[6] = __float2bfloat16(b.z); t[7] = __float2bfloat16(b.w);
    *(bf16x8*)&out[i] = *(const bf16x8*)t;
  }
}

// ---------------------------------------------------------------------------
// GEMM (r18-verified schedule): 4-phase/K-tile, BK=64, 2dbuf, 256x256 tile.
// P1: a0,a1 (8 reads) + b0 (4), stage B-lo(t+1); P2: a2,a3 (8), stage
// B-hi(t+1); P3: b1 (4), stage A-lo(t+2); P4: stage A-hi(t+2).
// Top-of-tile vmcnt(4); per-phase lgkm(0)+barriers (r14 race proofs).
// ---------------------------------------------------------------------------
template <typename OutT>
__global__ __launch_bounds__(512, 2) void gemm256(const bf16* __restrict__ A,
                                                  const bf16* __restrict__ B,
                                                  OutT* __restrict__ C,
                                                  int M, int N, int K) {
  const int nbn = N >> 8;
  const int nwg = gridDim.x;
  const int wg = blockIdx.x;
  const int cpx = nwg >> 3;                    // nwg % 8 == 0 guaranteed
  const int swz = (wg & 7) * cpx + (wg >> 3);  // XCD-aware swizzle (bijective)
  const int bm = swz / nbn;
  const int bn = swz - bm * nbn;

  __shared__ bf16 As[2][256][64];  // 64 KB (2 halves of 128 rows each)
  __shared__ bf16 Bs[2][256][64];  // 64 KB

  const int tid = threadIdx.x;
  const int wave = tid >> 6, lane = tid & 63;
  const int lo = lane & 15, hi = lane >> 4;
  const int wm = wave >> 2, wn = wave & 3;

  const bf16* Ag = A + (long)(bm * 256) * K;
  const bf16* Bg = B + (long)(bn * 256) * K;

  int srow[2], scol[2], sdst[2];
#pragma unroll
  for (int j = 0; j < 2; j++) {
    const int c = j * 512 + tid;
    const int row = c >> 3;                  // 0..127 within half
    srow[j] = row;
    scol[j] = ((c & 7) ^ (row & 7)) * 8;     // inverse-swizzled global col
    sdst[j] = (j * 512 + wave * 64) * 8;     // wave-uniform LDS base (elems)
  }

#define STG(G, S, kt, h)                                                      \
  {                                                                           \
    _Pragma("unroll") for (int j = 0; j < 2; j++)                             \
        gload16((G) + (long)((h)*128 + srow[j]) * K + (kt) + scol[j],         \
                (S) + (h)*8192 + sdst[j]);                                    \
  }

  f32x4 acc[8][4] = {};
  const int NT = K >> 6;

  // prologue: tile0 full (8 loads), tile1 A halves (4 loads)
  STG(Ag, &As[0][0][0], 0, 0); STG(Ag, &As[0][0][0], 0, 1);
  STG(Bg, &Bs[0][0][0], 0, 0); STG(Bg, &Bs[0][0][0], 0, 1);
  STG(Ag, &As[1][0][0], 64, 0); STG(Ag, &As[1][0][0], 64, 1);

#pragma unroll 1
  for (int t = 0; t < NT; ++t) {
    if (t >= NT - 1) asm volatile("s_waitcnt vmcnt(0)" ::: "memory");
    else             asm volatile("s_waitcnt vmcnt(4)" ::: "memory");
    __builtin_amdgcn_s_barrier();

    const bf16* Ab = &As[t & 1][0][0];
    const bf16* Bb = &Bs[t & 1][0][0];
    bf16* SAn = &As[t & 1][0][0];        // A(t+2) dest (dead after P2)
    bf16* SBn = &Bs[(t + 1) & 1][0][0];  // B(t+1) dest (other buffer)
    const int kt1 = (t + 1) * 64, kt2 = (t + 2) * 64;
    const bool s1 = (t + 1 < NT), s2 = (t + 2 < NT);
    const int c0 = (hi ^ (lo & 7)) * 8;        // ks0 swizzled col
    const int c1 = ((4 + hi) ^ (lo & 7)) * 8;  // ks1 swizzled col

    bf16x8 a0[4], a1[4], a2[4], a3[4], b0[4], b1[4];

    // ---- P1: af m0-3 both ks (8) + bfr ks0 (4); stage B-lo(t+1) ----
#pragma unroll
    for (int m = 0; m < 4; m++) {
      const int row = (wm * 128 + m * 16 + lo) * 64;
      a0[m] = *(const bf16x8*)&Ab[row + c0];
      a1[m] = *(const bf16x8*)&Ab[row + c1];
    }
#pragma unroll
    for (int n = 0; n < 4; n++)
      b0[n] = *(const bf16x8*)&Bb[(wn * 64 + n * 16 + lo) * 64 + c0];
    if (s1) STG(Bg, SBn, kt1, 0);
    __builtin_amdgcn_s_barrier();
    asm volatile("s_waitcnt lgkmcnt(0)" ::: "memory");
    __builtin_amdgcn_sched_barrier(0);
    __builtin_amdgcn_s_setprio(1);
#pragma unroll
    for (int m = 0; m < 4; m++)
#pragma unroll
      for (int n = 0; n < 4; n++) acc[m][n] = MFMA16(a0[m], b0[n], acc[m][n]);
    __builtin_amdgcn_s_setprio(0);
    __builtin_amdgcn_s_barrier();

    // ---- P2: af m4-7 both ks (8); stage B-hi(t+1) ----
#pragma unroll
    for (int m = 0; m < 4; m++) {
      const int row = (wm * 128 + 64 + m * 16 + lo) * 64;
      a2[m] = *(const bf16x8*)&Ab[row + c0];
      a3[m] = *(const bf16x8*)&Ab[row + c1];
    }
    if (s1) STG(Bg, SBn, kt1, 1);
    __builtin_amdgcn_s_barrier();
    asm volatile("s_waitcnt lgkmcnt(0)" ::: "memory");
    __builtin_amdgcn_sched_barrier(0);
    __builtin_amdgcn_s_setprio(1);
#pragma unroll
    for (int m = 0; m < 4; m++)
#pragma unroll
      for (int n = 0; n < 4; n++) acc[4 + m][n] = MFMA16(a2[m], b0[n], acc[4 + m][n]);
    __builtin_amdgcn_s_setprio(0);
    __builtin_amdgcn_s_barrier();

    // ---- P3: bfr ks1 (4); stage A-lo(t+2) (A(t) dead after P2) ----
#pragma unroll
    for (int n = 0; n < 4; n++)
      b1[n] = *(const bf16x8*)&Bb[(wn * 64 + n * 16 + lo) * 64 + c1];
    if (s2) STG(Ag, SAn, kt2, 0);
    __builtin_amdgcn_s_barrier();
    asm volatile("s_waitcnt lgkmcnt(0)" ::: "memory");
    __builtin_amdgcn_sched_barrier(0);
    __builtin_amdgcn_s_setprio(1);
#pragma unroll
    for (int m = 0; m < 4; m++)
#pragma unroll
      for (int n = 0; n < 4; n++) acc[m][n] = MFMA16(a1[m], b1[n], acc[m][n]);
    __builtin_amdgcn_s_setprio(0);
    __builtin_amdgcn_s_barrier();

    // ---- P4: no reads; stage A-hi(t+2) ----
    if (s2) STG(Ag, SAn, kt2, 1);
    __builtin_amdgcn_s_barrier();
    __builtin_amdgcn_s_setprio(1);
#pragma unroll
    for (int m = 0; m < 4; m++)
#pragma unroll
      for (int n = 0; n < 4; n++) acc[4 + m][n] = MFMA16(a3[m], b1[n], acc[4 + m][n]);
    __builtin_amdgcn_s_setprio(0);
    // tile-top vmcnt+barrier closes the tile
  }
#undef STG

  const long crow0 = (long)bm * 256 + wm * 128;
  const long ccol0 = (long)bn * 256 + wn * 64;
#pragma unroll
  for (int m = 0; m < 8; m++)
#pragma unroll
    for (int n = 0; n < 4; n++)
#pragma unroll
      for (int r = 0; r < 4; r++)
        stv(&C[(crow0 + m * 16 + hi * 4 + r) * (long)N + ccol0 + n * 16 + lo],
            acc[m][n][r]);
}

// ---------------------------------------------------------------------------
// Fused RoPE (in-place, Q scaled) + V transpose (disjoint qkv columns).
// Blocks [0,4096) = rope rows; [4096,5120) = vtrans 64x64 tiles. block 256.
// ---------------------------------------------------------------------------
__global__ void rope_vtrans(bf16* __restrict__ qkv, bf16* __restrict__ Vt) {
  __shared__ bf16 tile[64][65];
  if (blockIdx.x < 4096) {
    const int row = blockIdx.x;
    const int t = row & 2047;
    const float scale = 0.08838834764831845f;  // 128^-0.5
    for (int p = threadIdx.x; p < 40 * 64; p += blockDim.x) {
      const int sh = p >> 6, j = p & 63;
      const int kvh = sh / 5, slot = sh - kvh * 5;
      const long base = (long)row * 6144 + kvh * 768 + slot * 128 + j;
      const float x1 = __bfloat162float(qkv[base]);
      const float x2 = __bfloat162float(qkv[base + 64]);
      const float inv = __expf(-(float)j * 0.14391156831212787f);  // ln(1e4)/64
      const float ang = (float)t * inv;
      const float c = cosf(ang), s = sinf(ang);
      float o1 = x1 * c - x2 * s;
      float o2 = x2 * c + x1 * s;
      if (slot < 4) { o1 *= scale; o2 *= scale; }
      qkv[base] = __float2bfloat16(o1);
      qkv[base + 64] = __float2bfloat16(o2);
    }
  } else {
    const int id = blockIdx.x - 4096;
    const int tt = id & 31, dd = (id >> 5) & 1, bk = id >> 6;
    const int kvh = bk & 7, b = bk >> 3;
    const int tx = threadIdx.x & 63, ty = threadIdx.x >> 6;
    const bf16* src =
        qkv + ((long)(b * 2048 + tt * 64)) * 6144 + kvh * 768 + 640 + dd * 64;
    for (int r = ty; r < 64; r += 4) tile[r][tx] = src[(long)r * 6144 + tx];
    __syncthreads();
    bf16* dst = Vt + ((long)bk * 128 + dd * 64) * 2048 + tt * 64;
    for (int r = ty; r < 64; r += 4) dst[(long)r * 2048 + tx] = tile[tx][r];
  }
}

// ---------------------------------------------------------------------------
// Causal GQA flash attention (r18-verified): LDS-staged K/V, KVBLK=64,
// defer-max + DPP reductions. grid 512, block 256. XCD remap -> K/V in L2.
// ---------------------------------------------------------------------------
__global__ __launch_bounds__(256) void attn(const bf16* __restrict__ qkv,
                                            const bf16* __restrict__ Vt,
                                            bf16* __restrict__ Ctx) {
  const int lin = blockIdx.x;                 // 0..511
  const int c = (lin & 7) * 64 + (lin >> 3);  // XCD-contiguous chunks of 64
  const int z = c & 31;
  const int kvh = (c >> 5) & 7;
  const int b = c >> 8;

  const int tid = threadIdx.x;
  const int wave = tid >> 6;
  const int lane = tid & 63;
  const int h = kvh * 4 + wave;
  const int lo = lane & 15, hi = lane >> 4;

  const bf16* Qb = qkv + (long)b * 2048 * 6144 + kvh * 768 + wave * 128;
  const bf16* Kb = qkv + (long)b * 2048 * 6144 + kvh * 768 + 512;
  const bf16* Vb = Vt + ((long)(b * 8 + kvh)) * 128 * 2048;

  __shared__ bf16 Kl[2][64][128];   // 32 KB
  __shared__ bf16 Vl[2][128][64];   // 32 KB
  __shared__ bf16 Plds[4][32][40];  // 10 KB, per-wave

  const int kr0 = tid >> 4;
  const int kc = ((tid & 15) ^ (kr0 & 15)) * 8;
  const int vr0 = tid >> 3;
  const int vc = ((tid & 7) ^ (vr0 & 7)) * 8;
  const int wbase = wave * 512;

#define STAGE_KV(bufi, k0_)                                                    \
  {                                                                            \
    _Pragma("unroll") for (int cl = 0; cl < 4; cl++)                           \
        gload16(Kb + (long)((k0_) + cl * 16 + kr0) * 6144 + kc,                \
                &Kl[bufi][0][0] + cl * 2048 + wbase);                          \
    _Pragma("unroll") for (int cl = 0; cl < 4; cl++)                           \
        gload16(Vb + (long)(cl * 32 + vr0) * 2048 + (k0_) + vc,                \
                &Vl[bufi][0][0] + cl * 2048 + wbase);                          \
  }

#pragma unroll 1
  for (int pass = 0; pass < 2; ++pass) {
    const int qw = pass ? 63 - z : z;
    const int q0 = qw * 32;
    const int nkt = (qw >> 1) + 1;  // 64-wide tiles

    bf16x8 qf[2][4];
#pragma unroll
    for (int qb = 0; qb < 2; qb++)
#pragma unroll
      for (int dc = 0; dc < 4; dc++)
        qf[qb][dc] =
            *(const bf16x8*)&Qb[(long)(q0 + qb * 16 + lo) * 6144 + dc * 32 + hi * 8];

    f32x4 acc[2][8] = {};
    float mrow[2][4], lrow[2][4];
#pragma unroll
    for (int qb = 0; qb < 2; qb++)
#pragma unroll
      for (int r = 0; r < 4; r++) {
        mrow[qb][r] = -1e30f;
        lrow[qb][r] = 0.0f;
      }

    STAGE_KV(0, 0);
    if (nkt > 1) STAGE_KV(1, 64);

#pragma unroll 1
    for (int kt = 0; kt < nkt; ++kt) {
      if (kt < nkt - 1) asm volatile("s_waitcnt vmcnt(8)" ::: "memory");
      else              asm volatile("s_waitcnt vmcnt(0)" ::: "memory");
      __builtin_amdgcn_s_barrier();

      const int bi = kt & 1;
      const int k0 = kt * 64;

      f32x4 sacc[2][4] = {};
      __builtin_amdgcn_s_setprio(1);
#pragma unroll
      for (int kb = 0; kb < 4; kb++)
#pragma unroll
        for (int dc = 0; dc < 4; dc++) {
          const int row = kb * 16 + lo;
          const int p = (dc * 4 + hi) ^ lo;  // row&15 == lo
          const bf16x8 kf = *(const bf16x8*)&Kl[bi][row][p * 8];
          sacc[0][kb] = MFMA16(qf[0][dc], kf, sacc[0][kb]);
          sacc[1][kb] = MFMA16(qf[1][dc], kf, sacc[1][kb]);
        }
      __builtin_amdgcn_s_setprio(0);

      if (kt == nkt - 1) {  // diagonal region: mask k > q
#pragma unroll
        for (int qb = 0; qb < 2; qb++)
#pragma unroll
          for (int kb = 0; kb < 4; kb++) {
            const int q = q0 + qb * 16 + hi * 4;
            const int k = k0 + kb * 16 + lo;
#pragma unroll
            for (int r = 0; r < 4; r++)
              if (k > q + r) sacc[qb][kb][r] = -1e30f;
          }
      }

      // defer-max: lane-local excess check (no cross-lane ops)
      float ex = -1.0f;
#pragma unroll
      for (int qb = 0; qb < 2; qb++)
#pragma unroll
        for (int kb = 0; kb < 4; kb++)
#pragma unroll
          for (int r = 0; r < 4; r++)
            ex = fmaxf(ex, sacc[qb][kb][r] - mrow[qb][r]);

      if (!__all(ex <= 0.0f)) {
        float sf[2][4];
#pragma unroll
        for (int qb = 0; qb < 2; qb++)
#pragma unroll
          for (int r = 0; r < 4; r++) {
            const float pm = row_max16(
                fmaxf(fmaxf(sacc[qb][0][r], sacc[qb][1][r]),
                      fmaxf(sacc[qb][2][r], sacc[qb][3][r])));
            const float mn = fmaxf(mrow[qb][r], pm);
            sf[qb][r] = __expf(mrow[qb][r] - mn);
            mrow[qb][r] = mn;
            lrow[qb][r] *= sf[qb][r];
          }
#pragma unroll
        for (int qb = 0; qb < 2; qb++)
#pragma unroll
          for (int dt = 0; dt < 8; dt++)
#pragma unroll
            for (int r = 0; r < 4; r++) acc[qb][dt][r] *= sf[qb][r];
      }

      // exp in place + one row-sum per (qb,r) per 64 keys
#pragma unroll
      for (int qb = 0; qb < 2; qb++)
#pragma unroll
        for (int r = 0; r < 4; r++) {
          float s0 = __expf(sacc[qb][0][r] - mrow[qb][r]);
          float s1 = __expf(sacc[qb][1][r] - mrow[qb][r]);
          float s2 = __expf(sacc[qb][2][r] - mrow[qb][r]);
          float s3 = __expf(sacc[qb][3][r] - mrow[qb][r]);
          sacc[qb][0][r] = s0; sacc[qb][1][r] = s1;
          sacc[qb][2][r] = s2; sacc[qb][3][r] = s3;
          lrow[qb][r] += row_sum16((s0 + s1) + (s2 + s3));
        }

      // PV in two 32-wide chunks through per-wave Plds (in-order: safe)
#pragma unroll
      for (int ks = 0; ks < 2; ks++) {
#pragma unroll
        for (int qb = 0; qb < 2; qb++)
#pragma unroll
          for (int r = 0; r < 4; r++) {
            Plds[wave][qb * 16 + hi * 4 + r][lo] =
                __float2bfloat16(sacc[qb][ks * 2][r]);
            Plds[wave][qb * 16 + hi * 4 + r][16 + lo] =
                __float2bfloat16(sacc[qb][ks * 2 + 1][r]);
          }

        bf16x8 pa[2];
#pragma unroll
        for (int qb = 0; qb < 2; qb++)
          pa[qb] = *(const bf16x8*)&Plds[wave][qb * 16 + lo][hi * 8];

        __builtin_amdgcn_s_setprio(1);
#pragma unroll
        for (int dt = 0; dt < 8; dt++) {
          const int row = dt * 16 + lo;
          const int p = (ks * 4 + hi) ^ (row & 7);
          const bf16x8 vf = *(const bf16x8*)&Vl[bi][row][p * 8];
          acc[0][dt] = MFMA16(pa[0], vf, acc[0][dt]);
          acc[1][dt] = MFMA16(pa[1], vf, acc[1][dt]);
        }
        __builtin_amdgcn_s_setprio(0);
      }

      asm volatile("s_waitcnt lgkmcnt(0)" ::: "memory");
      __builtin_amdgcn_s_barrier();
      if (kt + 2 < nkt) STAGE_KV(bi, (kt + 2) * 64);
    }

    // epilogue: reciprocal once per row, then 64 muls
#pragma unroll
    for (int qb = 0; qb < 2; qb++)
#pragma unroll
      for (int r = 0; r < 4; r++) {
        const float rl = 1.0f / lrow[qb][r];
#pragma unroll
        for (int dt = 0; dt < 8; dt++) {
          const float o = acc[qb][dt][r] * rl;
          const long row = (long)b * 2048 + q0 + qb * 16 + hi * 4 + r;
          Ctx[row * 4096 + h * 128 + dt * 16 + lo] = __float2bfloat16(o);
        }
      }
  }
#undef STAGE_KV
}

// ---------------------------------------------------------------------------

extern "C" void kernel_launch(void* const* d_in, const int* in_sizes, int n_in,
                              void* d_out, int out_size, void* d_ws, size_t ws_size,
                              hipStream_t stream) {
  (void)in_sizes; (void)n_in; (void)out_size; (void)ws_size;
  const float* x = (const float*)d_in[0];      // [2,2048,4096] fp32
  const float* wqkv = (const float*)d_in[1];   // [6144,4096] fp32
  const float* wo = (const float*)d_in[2];     // [4096,4096] fp32
  float* out = (float*)d_out;                  // [2,2048,4096] fp32

  const long NX = 4096L * 4096;
  const long NW1 = 6144L * 4096;

  const size_t XB_B = (size_t)NX * 2;
  const size_t WQ_B = (size_t)NW1 * 2;
  const size_t QKV_B = WQ_B;

  char* w = (char*)d_ws;
  bf16* xb = (bf16*)w;                 // later: wob
  bf16* wqkvb = (bf16*)(w + XB_B);     // later: ctx
  bf16* qkvp = (bf16*)(w + XB_B + WQ_B);
  bf16* Vtp = (bf16*)(w + XB_B + WQ_B + QKV_B);
  bf16* wob = xb;
  bf16* ctx = wqkvb;

  // 1. merged casts for GEMM1 (one launch)
  cast2_f32_bf16<<<3072, 256, 0, stream>>>(x, xb, NX, wqkv, wqkvb, NW1);

  // 2. QKV projection: qkv[4096,6144] = xb @ wqkvb^T   (16x24 = 384 tiles)
  gemm256<bf16><<<16 * 24, 512, 0, stream>>>(xb, wqkvb, qkvp, 4096, 6144, 4096);

  // 3. fused RoPE (Q scaled, in-place) + V transpose (disjoint columns)
  rope_vtrans<<<4096 + 1024, 256, 0, stream>>>(qkvp, Vtp);

  // 4. cast wo into xb's space (xb dead after GEMM1; placed here so its
  //    traffic cannot evict GEMM1's inputs -- r23 lesson)
  cast_f32_bf16<<<2048, 256, 0, stream>>>(wo, wob, NX);

  // 5. attention -> ctx (wqkvb's space, dead after GEMM1)
  attn<<<dim3(512), 256, 0, stream>>>(qkvp, Vtp, ctx);

  // 6. output projection: out(fp32) = ctx @ wob^T  (256 blocks = 1 round)
  gemm256<float><<<16 * 16, 512, 0, stream>>>(ctx, wob, out, 4096, 4096, 4096);
}